// Round 4
// baseline (629.066 us; speedup 1.0000x reference)
//
#include <hip/hip_runtime.h>
#include <hip/hip_bf16.h>

// B=128, N=256, D=H=256. out = [weighted (B*N*D), attention (B*N*N)] fp32.
// rho per batch via Gelfand: 12 normalized squarings (m=4096), norms fused.
// sq0 (fp32->fp32) and sq1 (fp32->bf16) use split-bf16 3-MFMA precision;
// sq2..sq11 run pure bf16 with register-direct fragment loads (M + M^T stored).
// sigma: power iteration from LDS-cached bf16 W, final sigma in fp32.

#define NB 128
#define MAT 65536
#define BIG 8388608LL

typedef __attribute__((ext_vector_type(4))) float floatx4;
typedef __attribute__((ext_vector_type(4))) float f4v;
typedef __attribute__((ext_vector_type(8))) short short8v;
typedef __attribute__((ext_vector_type(4))) short short4v;

__device__ __forceinline__ short f2bf(float x) {
  union { float f; unsigned u; } v; v.f = x;
  unsigned r = v.u + 0x7fff + ((v.u >> 16) & 1);
  return (short)(r >> 16);
}
__device__ __forceinline__ float bf2f(short h) {
  union { unsigned u; float f; } v; v.u = ((unsigned)(unsigned short)h) << 16; return v.f;
}

// ---------------- generic split-bf16 GEMM (projections, scores, sq0, final) ---------
// C[bz] = alpha * A[bz] @ B[bz](^T) + bias, optional fused Frobenius norm^2,
// optional fused attention write (att_out = A * att_scale[bz], n0==0 blocks).
// smode: 0 alpha=1, 1 alpha=1/scale[bz*sstride], 2 alpha=scale[bz*sstride].
template<bool TB, bool BATCHED>
__global__ __launch_bounds__(256) void gemm_mfma(
    const float* __restrict__ A, const float* __restrict__ B, float* __restrict__ C,
    long long sA, long long sB, long long sC,
    const float* __restrict__ bias,
    const float* __restrict__ scale_ptr, int sstride, int smode,
    float* __restrict__ norm_out,
    float* __restrict__ att_out, const float* __restrict__ att_scale)
{
  __shared__ short sAhi[128 * 32], sAlo[128 * 32];
  __shared__ short sBhi[128 * 40], sBlo[128 * 40];

  int bz, m0, n0;
  if (BATCHED) {
    int lin = blockIdx.x;
    int xcd = lin & 7;
    int s = lin >> 3;
    bz = xcd * 16 + (s >> 2);
    int tile = s & 3;
    m0 = (tile >> 1) * 128;
    n0 = (tile & 1) * 128;
  } else {
    bz = blockIdx.z;
    m0 = blockIdx.y * 128;
    n0 = blockIdx.x * 128;
  }
  A += (long long)bz * sA;
  B += (long long)bz * sB;
  C += (long long)bz * sC;

  const int t = threadIdx.x;
  const int lane = t & 63;
  const int wave = t >> 6;
  const int wm = wave >> 1, wn = wave & 1;
  const int q = lane >> 4, c16 = lane & 15;

  float rinv_att = 0.f;
  const bool do_att = (att_out != nullptr) && (n0 == 0);
  if (do_att) rinv_att = att_scale[bz];

  floatx4 acc[4][4];
  #pragma unroll
  for (int i = 0; i < 4; i++)
    #pragma unroll
    for (int j = 0; j < 4; j++)
      acc[i][j] = (floatx4){0.f, 0.f, 0.f, 0.f};

  for (int k0 = 0; k0 < 256; k0 += 32) {
    #pragma unroll
    for (int i = 0; i < 4; i++) {
      int f = t + i * 256;
      int row = f >> 3, c4 = f & 7;
      f4v v = *(const f4v*)(A + (long long)(m0 + row) * 256 + k0 + c4 * 4);
      if (do_att)
        *(f4v*)(att_out + (long long)bz * MAT + (long long)(m0 + row) * 256 + k0 + c4 * 4)
            = v * rinv_att;
      short4v h, l;
      #pragma unroll
      for (int e = 0; e < 4; e++) {
        short hh = f2bf(v[e]);
        h[e] = hh;
        l[e] = f2bf(v[e] - bf2f(hh));
      }
      *(short4v*)&sAhi[row * 32 + c4 * 4] = h;
      *(short4v*)&sAlo[row * 32 + c4 * 4] = l;
    }
    if (TB) {
      #pragma unroll
      for (int i = 0; i < 4; i++) {
        int f = t + i * 256;
        int row = f >> 3, c4 = f & 7;
        f4v v = *(const f4v*)(B + (long long)(n0 + row) * 256 + k0 + c4 * 4);
        short4v h, l;
        #pragma unroll
        for (int e = 0; e < 4; e++) {
          short hh = f2bf(v[e]);
          h[e] = hh;
          l[e] = f2bf(v[e] - bf2f(hh));
        }
        *(short4v*)&sBhi[row * 40 + c4 * 4] = h;
        *(short4v*)&sBlo[row * 40 + c4 * 4] = l;
      }
      __syncthreads();
    } else {
      __shared__ float sT[32 * 132];
      #pragma unroll
      for (int i = 0; i < 4; i++) {
        int f = t + i * 256;
        int kk = f >> 5, n4 = f & 31;
        f4v v = *(const f4v*)(B + (long long)(k0 + kk) * 256 + n0 + n4 * 4);
        *(f4v*)&sT[kk * 132 + n4 * 4] = v;
      }
      __syncthreads();
      int n = t & 127, kh = t >> 7;
      short8v h0, h1, l0, l1;
      #pragma unroll
      for (int j = 0; j < 8; j++) {
        float x0 = sT[(kh * 16 + j) * 132 + n];
        float x1 = sT[(kh * 16 + 8 + j) * 132 + n];
        short a0 = f2bf(x0), a1 = f2bf(x1);
        h0[j] = a0; l0[j] = f2bf(x0 - bf2f(a0));
        h1[j] = a1; l1[j] = f2bf(x1 - bf2f(a1));
      }
      *(short8v*)&sBhi[n * 40 + kh * 16] = h0;
      *(short8v*)&sBhi[n * 40 + kh * 16 + 8] = h1;
      *(short8v*)&sBlo[n * 40 + kh * 16] = l0;
      *(short8v*)&sBlo[n * 40 + kh * 16 + 8] = l1;
      __syncthreads();
    }

    short8v ah[4], al[4], bh[4], bl[4];
    #pragma unroll
    for (int fi = 0; fi < 4; fi++) {
      int r = wm * 64 + fi * 16 + c16;
      ah[fi] = *(short8v*)&sAhi[r * 32 + q * 8];
      al[fi] = *(short8v*)&sAlo[r * 32 + q * 8];
    }
    #pragma unroll
    for (int fj = 0; fj < 4; fj++) {
      int r = wn * 64 + fj * 16 + c16;
      bh[fj] = *(short8v*)&sBhi[r * 40 + q * 8];
      bl[fj] = *(short8v*)&sBlo[r * 40 + q * 8];
    }
    #pragma unroll
    for (int fi = 0; fi < 4; fi++)
      #pragma unroll
      for (int fj = 0; fj < 4; fj++) {
        acc[fi][fj] = __builtin_amdgcn_mfma_f32_16x16x32_bf16(al[fi], bh[fj], acc[fi][fj], 0, 0, 0);
        acc[fi][fj] = __builtin_amdgcn_mfma_f32_16x16x32_bf16(ah[fi], bl[fj], acc[fi][fj], 0, 0, 0);
        acc[fi][fj] = __builtin_amdgcn_mfma_f32_16x16x32_bf16(ah[fi], bh[fj], acc[fi][fj], 0, 0, 0);
      }
    __syncthreads();
  }

  float alpha = 1.0f;
  if (smode == 1) alpha = 1.0f / scale_ptr[bz * sstride];
  else if (smode == 2) alpha = scale_ptr[bz * sstride];

  float ssq = 0.f;
  #pragma unroll
  for (int fi = 0; fi < 4; fi++) {
    #pragma unroll
    for (int fj = 0; fj < 4; fj++) {
      int col = n0 + wn * 64 + fj * 16 + c16;
      float bb = bias ? bias[col] : 0.f;
      #pragma unroll
      for (int r = 0; r < 4; r++) {
        int row = m0 + wm * 64 + fi * 16 + q * 4 + r;
        float v = acc[fi][fj][r] * alpha + bb;
        C[(long long)row * 256 + col] = v;
        ssq += v * v;
      }
    }
  }

  if (norm_out) {
    float* red = (float*)sAhi;
    red[t] = ssq;
    __syncthreads();
    for (int off = 128; off > 0; off >>= 1) {
      if (t < off) red[t] += red[t + off];
      __syncthreads();
    }
    if (t == 0) atomicAdd(&norm_out[bz], red[0]);
  }
}

// ---------------- chain epilogue helper: alpha*acc -> bf16 M + M^T + norm ----------
__device__ __forceinline__ void chain_epilogue(
    short* LB, float* red, floatx4 (&acc)[4][4], float alpha,
    int m0, int n0, int wm, int wn, int q, int c16, int t,
    short* __restrict__ Mout, short* __restrict__ MTout,
    float* __restrict__ nout, int bz, bool write_out)
{
  float ssq = 0.f;
  #pragma unroll
  for (int fi = 0; fi < 4; fi++)
    #pragma unroll
    for (int fj = 0; fj < 4; fj++) {
      int lcol = wn * 64 + fj * 16 + c16;
      #pragma unroll
      for (int r = 0; r < 4; r++) {
        int lrow = wm * 64 + fi * 16 + q * 4 + r;
        float v = acc[fi][fj][r] * alpha;
        ssq += v * v;
        if (write_out) LB[lrow * 128 + lcol] = f2bf(v);
      }
    }

  if (write_out) {
    __syncthreads();
    int lr = t >> 1, off = (t & 1) * 64;
    #pragma unroll
    for (int jc = 0; jc < 8; jc++)
      *(short8v*)(Mout + (long long)(m0 + lr) * 256 + n0 + off + jc * 8)
          = *(const short8v*)&LB[lr * 128 + off + jc * 8];
    #pragma unroll
    for (int jc = 0; jc < 8; jc++) {
      short8v tv;
      #pragma unroll
      for (int jj = 0; jj < 8; jj++)
        tv[jj] = LB[(off + jc * 8 + jj) * 128 + lr];
      *(short8v*)(MTout + (long long)(n0 + lr) * 256 + m0 + off + jc * 8) = tv;
    }
  }

  red[t] = ssq;
  __syncthreads();
  for (int off2 = 128; off2 > 0; off2 >>= 1) {
    if (t < off2) red[t] += red[t + off2];
    __syncthreads();
  }
  if (t == 0) atomicAdd(&nout[bz], red[0]);
}

// ---------------- sq1: fp32 in (split 3-MFMA) -> bf16 M + M^T out ------------------
__global__ __launch_bounds__(256) void sq_f32bf(
    const float* __restrict__ A, short* __restrict__ chain_out,
    const float* __restrict__ nprev, float* __restrict__ nout)
{
  __shared__ short SM[18432];           // sAhi|sAlo|sBhi|sBlo ; reused as LB (16384)
  __shared__ float sT[32 * 132];
  __shared__ float red[256];
  short* sAhi = SM;
  short* sAlo = SM + 4096;
  short* sBhi = SM + 8192;
  short* sBlo = SM + 13312;

  int lin = blockIdx.x;
  int xcd = lin & 7, s = lin >> 3;
  int bz = xcd * 16 + (s >> 2);
  int m0 = ((s >> 1) & 1) * 128, n0 = (s & 1) * 128;
  A += (long long)bz * MAT;

  const int t = threadIdx.x;
  const int lane = t & 63;
  const int wave = t >> 6;
  const int wm = wave >> 1, wn = wave & 1;
  const int q = lane >> 4, c16 = lane & 15;

  floatx4 acc[4][4];
  #pragma unroll
  for (int i = 0; i < 4; i++)
    #pragma unroll
    for (int j = 0; j < 4; j++)
      acc[i][j] = (floatx4){0.f, 0.f, 0.f, 0.f};

  for (int k0 = 0; k0 < 256; k0 += 32) {
    #pragma unroll
    for (int i = 0; i < 4; i++) {
      int f = t + i * 256;
      int row = f >> 3, c4 = f & 7;
      f4v v = *(const f4v*)(A + (long long)(m0 + row) * 256 + k0 + c4 * 4);
      short4v h, l;
      #pragma unroll
      for (int e = 0; e < 4; e++) {
        short hh = f2bf(v[e]);
        h[e] = hh;
        l[e] = f2bf(v[e] - bf2f(hh));
      }
      *(short4v*)&sAhi[row * 32 + c4 * 4] = h;
      *(short4v*)&sAlo[row * 32 + c4 * 4] = l;
    }
    #pragma unroll
    for (int i = 0; i < 4; i++) {
      int f = t + i * 256;
      int kk = f >> 5, n4 = f & 31;
      f4v v = *(const f4v*)(A + (long long)(k0 + kk) * 256 + n0 + n4 * 4);
      *(f4v*)&sT[kk * 132 + n4 * 4] = v;
    }
    __syncthreads();
    {
      int n = t & 127, kh = t >> 7;
      short8v h0, h1, l0, l1;
      #pragma unroll
      for (int j = 0; j < 8; j++) {
        float x0 = sT[(kh * 16 + j) * 132 + n];
        float x1 = sT[(kh * 16 + 8 + j) * 132 + n];
        short a0 = f2bf(x0), a1 = f2bf(x1);
        h0[j] = a0; l0[j] = f2bf(x0 - bf2f(a0));
        h1[j] = a1; l1[j] = f2bf(x1 - bf2f(a1));
      }
      *(short8v*)&sBhi[n * 40 + kh * 16] = h0;
      *(short8v*)&sBhi[n * 40 + kh * 16 + 8] = h1;
      *(short8v*)&sBlo[n * 40 + kh * 16] = l0;
      *(short8v*)&sBlo[n * 40 + kh * 16 + 8] = l1;
    }
    __syncthreads();

    short8v ah[4], al[4], bh[4], bl[4];
    #pragma unroll
    for (int fi = 0; fi < 4; fi++) {
      int r = wm * 64 + fi * 16 + c16;
      ah[fi] = *(short8v*)&sAhi[r * 32 + q * 8];
      al[fi] = *(short8v*)&sAlo[r * 32 + q * 8];
    }
    #pragma unroll
    for (int fj = 0; fj < 4; fj++) {
      int r = wn * 64 + fj * 16 + c16;
      bh[fj] = *(short8v*)&sBhi[r * 40 + q * 8];
      bl[fj] = *(short8v*)&sBlo[r * 40 + q * 8];
    }
    #pragma unroll
    for (int fi = 0; fi < 4; fi++)
      #pragma unroll
      for (int fj = 0; fj < 4; fj++) {
        acc[fi][fj] = __builtin_amdgcn_mfma_f32_16x16x32_bf16(al[fi], bh[fj], acc[fi][fj], 0, 0, 0);
        acc[fi][fj] = __builtin_amdgcn_mfma_f32_16x16x32_bf16(ah[fi], bl[fj], acc[fi][fj], 0, 0, 0);
        acc[fi][fj] = __builtin_amdgcn_mfma_f32_16x16x32_bf16(ah[fi], bh[fj], acc[fi][fj], 0, 0, 0);
      }
    __syncthreads();
  }

  float alpha = 1.0f / nprev[0 + bz * 0];   // nprev is a single slot base + bz? see launch
  alpha = 1.0f / nprev[bz];                 // per-batch norm slot
  short* Mout = chain_out + (long long)bz * 131072;
  short* MTout = Mout + 65536;
  chain_epilogue(SM, red, acc, alpha, m0, n0, wm, wn, q, c16, t,
                 Mout, MTout, nout, bz, true);
}

// ---------------- sq2..sq11: pure bf16, register-direct fragments ------------------
template<bool WRITE_OUT>
__global__ __launch_bounds__(256) void sq_bf(
    const short* __restrict__ chain_in, short* __restrict__ chain_out,
    const float* __restrict__ nprev, float* __restrict__ nout)
{
  __shared__ short LB[16384];
  __shared__ float red[256];

  int lin = blockIdx.x;
  int xcd = lin & 7, s = lin >> 3;
  int bz = xcd * 16 + (s >> 2);
  int m0 = ((s >> 1) & 1) * 128, n0 = (s & 1) * 128;

  const short* Arow = chain_in + (long long)bz * 131072;
  const short* Brow = Arow + 65536;  // M^T

  const int t = threadIdx.x;
  const int lane = t & 63;
  const int wave = t >> 6;
  const int wm = wave >> 1, wn = wave & 1;
  const int q = lane >> 4, c16 = lane & 15;

  floatx4 acc[4][4];
  #pragma unroll
  for (int i = 0; i < 4; i++)
    #pragma unroll
    for (int j = 0; j < 4; j++)
      acc[i][j] = (floatx4){0.f, 0.f, 0.f, 0.f};

  #pragma unroll
  for (int k0 = 0; k0 < 256; k0 += 32) {
    short8v a[4], b[4];
    #pragma unroll
    for (int fi = 0; fi < 4; fi++)
      a[fi] = *(const short8v*)(Arow + (long long)(m0 + wm * 64 + fi * 16 + c16) * 256 + k0 + q * 8);
    #pragma unroll
    for (int fj = 0; fj < 4; fj++)
      b[fj] = *(const short8v*)(Brow + (long long)(n0 + wn * 64 + fj * 16 + c16) * 256 + k0 + q * 8);
    #pragma unroll
    for (int fi = 0; fi < 4; fi++)
      #pragma unroll
      for (int fj = 0; fj < 4; fj++)
        acc[fi][fj] = __builtin_amdgcn_mfma_f32_16x16x32_bf16(a[fi], b[fj], acc[fi][fj], 0, 0, 0);
  }

  float alpha = 1.0f / nprev[bz];
  short* Mout = WRITE_OUT ? chain_out + (long long)bz * 131072 : nullptr;
  short* MTout = WRITE_OUT ? Mout + 65536 : nullptr;
  chain_epilogue(LB, red, acc, alpha, m0, n0, wm, wn, q, c16, t,
                 Mout, MTout, nout, bz, WRITE_OUT);
}

// ---------------- rho finalize / sigma ---------------------------------------------
__global__ void finalize_rho(const float* __restrict__ norm2, float* __restrict__ rho_inv) {
  int b = threadIdx.x;
  if (b < NB) {
    float acc = 0.f, w = 1.0f;
    for (int i = 0; i <= 12; i++) {
      acc += w * 0.5f * logf(norm2[i * NB + b]);
      w *= 0.5f;
    }
    rho_inv[b] = expf(-acc);
  }
}

__device__ __forceinline__ float block_sum(float x, float* red, int t)
{
  red[t] = x; __syncthreads();
  for (int off = 128; off > 0; off >>= 1) {
    if (t < off) red[t] += red[t + off];
    __syncthreads();
  }
  float r = red[0];
  __syncthreads();
  return r;
}

// Power iteration with W cached in LDS as bf16; final sigma = ||W v5|| in fp32.
// Also zeroes the norm2 accumulator array (13*128 floats).
__global__ __launch_bounds__(256) void sigma_kernel(
    const float* __restrict__ W, const float* __restrict__ u0, float* __restrict__ sigma,
    float* __restrict__ norm2zero)
{
  __shared__ short Wl[65536];
  __shared__ float u[256], v[256], red[256];
  int t = threadIdx.x;
  const float eps = 1e-12f;

  #pragma unroll
  for (int i = 0; i < 7; i++) {
    int j = t + i * 256;
    if (j < 13 * NB) norm2zero[j] = 0.f;
  }

  // load W -> LDS bf16 (coalesced)
  for (int i = 0; i < 64; i++) {
    int idx = (i * 256 + t) * 4;
    f4v w = *(const f4v*)(W + idx);
    short4v h;
    #pragma unroll
    for (int e = 0; e < 4; e++) h[e] = f2bf(w[e]);
    *(short4v*)&Wl[idx] = h;
  }

  float x = u0[t];
  float nrm = sqrtf(block_sum(x * x, red, t));
  u[t] = x / (nrm + eps);
  __syncthreads();

  for (int it = 0; it < 5; it++) {
    // v = l2n(W^T u): thread t owns column t
    float s = 0.f;
    #pragma unroll 8
    for (int h = 0; h < 256; h++)
      s = fmaf(bf2f(Wl[h * 256 + t]), u[h], s);
    nrm = sqrtf(block_sum(s * s, red, t));
    v[t] = s / (nrm + eps);
    __syncthreads();
    if (it < 4) {
      // u = l2n(W v): thread t owns row t
      float r2 = 0.f;
      #pragma unroll 8
      for (int d = 0; d < 64; d++) {
        short4v w4 = *(const short4v*)&Wl[t * 256 + d * 4];
        f4v vv = *(const f4v*)&v[d * 4];
        r2 += bf2f(w4[0]) * vv[0] + bf2f(w4[1]) * vv[1]
            + bf2f(w4[2]) * vv[2] + bf2f(w4[3]) * vv[3];
      }
      nrm = sqrtf(block_sum(r2 * r2, red, t));
      u[t] = r2 / (nrm + eps);
      __syncthreads();
    }
  }

  // z = W v5 in fp32 from global; sigma = ||z||
  float z = 0.f;
  #pragma unroll 8
  for (int d = 0; d < 64; d++) {
    f4v w = *(const f4v*)(W + t * 256 + d * 4);
    f4v vv = *(const f4v*)&v[d * 4];
    z += w[0] * vv[0] + w[1] * vv[1] + w[2] * vv[2] + w[3] * vv[3];
  }
  float zz = block_sum(z * z, red, t);
  if (t == 0) sigma[0] = sqrtf(zz);
}

extern "C" void kernel_launch(void* const* d_in, const int* in_sizes, int n_in,
                              void* d_out, int out_size, void* d_ws, size_t ws_size,
                              hipStream_t stream)
{
  const float* x  = (const float*)d_in[0];
  const float* Wq = (const float*)d_in[1];
  const float* bq = (const float*)d_in[2];
  const float* Wk = (const float*)d_in[3];
  const float* bk = (const float*)d_in[4];
  const float* Wv = (const float*)d_in[5];
  const float* bv = (const float*)d_in[6];
  const float* u0 = (const float*)d_in[7];

  float* out  = (float*)d_out;
  float* out0 = out;             // q -> sq0 fp32 -> even bf16 chain -> weighted
  float* out1 = out + BIG;       // k -> odd bf16 chain -> attention
  short* out0s = (short*)out0;
  short* out1s = (short*)out1;

  float* ws      = (float*)d_ws;
  float* scores_buf = ws;        // [B,N,N] raw scores
  float* vals_buf   = ws + BIG;  // [B,N,D] vals
  float* norm2   = ws + 2 * BIG; // [13][128]
  float* sigma   = norm2 + 13 * NB;
  float* rho_inv = sigma + 1;    // [128]

  dim3 blk(256);

  // sigma power iteration (also zeroes norm2)
  sigma_kernel<<<1, blk, 0, stream>>>(Wv, u0, sigma, norm2);

  // q -> out0 ; k -> out1
  gemm_mfma<true, false><<<dim3(2, 256, 1), blk, 0, stream>>>(x, Wq, out0, 0, 0, 0,
      bq, nullptr, 0, 0, nullptr, nullptr, nullptr);
  gemm_mfma<true, false><<<dim3(2, 256, 1), blk, 0, stream>>>(x, Wk, out1, 0, 0, 0,
      bk, nullptr, 0, 0, nullptr, nullptr, nullptr);

  // scores = q @ k^T -> ws, norm slot 0
  gemm_mfma<true, true><<<dim3(512, 1, 1), blk, 0, stream>>>(out0, out1, scores_buf,
      MAT, MAT, MAT, nullptr, nullptr, 0, 0, norm2, nullptr, nullptr);

  // vals = (x @ Wv^T)/sigma + bv -> ws
  gemm_mfma<true, false><<<dim3(2, 256, 1), blk, 0, stream>>>(x, Wv, vals_buf, 0, 0, 0,
      bv, sigma, 0, 1, nullptr, nullptr, nullptr);

  // sq0: scores (fp32) -> out0 fp32, alpha=1/n0^2, norm slot 1
  gemm_mfma<false, true><<<dim3(512, 1, 1), blk, 0, stream>>>(scores_buf, scores_buf, out0,
      MAT, MAT, MAT, nullptr, norm2, 1, 1, norm2 + NB, nullptr, nullptr);

  // sq1: out0 fp32 -> out1 bf16 (M + M^T), alpha=1/n1^2, norm slot 2
  sq_f32bf<<<dim3(512, 1, 1), blk, 0, stream>>>(out0, out1s, norm2 + NB, norm2 + 2 * NB);

  // sq2..sq11: bf16 chain; sq11 norm-only
  const short* cin = out1s;
  for (int i = 2; i <= 11; i++) {
    if (i < 11) {
      short* cout = (i % 2 == 0) ? out0s : out1s;
      sq_bf<true><<<dim3(512, 1, 1), blk, 0, stream>>>(cin, cout,
          norm2 + i * NB, norm2 + (i + 1) * NB);
      cin = cout;
    } else {
      sq_bf<false><<<dim3(512, 1, 1), blk, 0, stream>>>(cin, nullptr,
          norm2 + i * NB, norm2 + (i + 1) * NB);
    }
  }
  finalize_rho<<<1, 128, 0, stream>>>(norm2, rho_inv);

  // weighted = (scores @ vals) * rho_inv -> out0 ;
  // attention = scores * rho_inv -> out1 (fused into A-staging, n0==0 blocks)
  gemm_mfma<false, true><<<dim3(512, 1, 1), blk, 0, stream>>>(scores_buf, vals_buf, out0,
      MAT, MAT, MAT, nullptr, rho_inv, 1, 2, nullptr, out1, rho_inv);
}

// Round 6
// 504.526 us; speedup vs baseline: 1.2468x; 1.2468x over previous
//
#include <hip/hip_runtime.h>
#include <hip/hip_bf16.h>

// B=128, N=256, D=H=256. out = [weighted (B*N*D), attention (B*N*N)] fp32.
// rho per batch via Gelfand: 12 normalized squarings (m=4096).
//   squaring 1: fp32 scores -> bf16 M1 (split-bf16 3-MFMA), slot1
//   squarings 2..11: pure bf16, M-only storage, LDS-transposed B tiles (L2-resident)
//   squaring 12: norm-only. rho finalized inline in the final GEMM.
// Projections q/k/vals fused in one launch (vals stored RAW; 1/sigma + bv applied
// in the final GEMM's B-staging). sigma: 1024-thread LDS power iteration.

#define NB 128
#define MAT 65536
#define BIG 8388608LL

typedef __attribute__((ext_vector_type(4))) float floatx4;
typedef __attribute__((ext_vector_type(4))) float f4v;
typedef __attribute__((ext_vector_type(8))) short short8v;
typedef __attribute__((ext_vector_type(4))) short short4v;

__device__ __forceinline__ short f2bf(float x) {
  union { float f; unsigned u; } v; v.f = x;
  unsigned r = v.u + 0x7fff + ((v.u >> 16) & 1);
  return (short)(r >> 16);
}
__device__ __forceinline__ float bf2f(short h) {
  union { unsigned u; float f; } v; v.u = ((unsigned)(unsigned short)h) << 16; return v.f;
}

// ---------------- generic split-bf16 GEMM ------------------------------------------
// smode: 0 alpha=1, 1 alpha=1/scale[bz], 2 alpha=scale[bz],
//        3 alpha = rho_inv computed inline from partials (scale_ptr = partials base).
// Non-batched grid (2*nsel, 256): sel = blockIdx.x>>1 picks (B,bias,C) / (B2,bias2,C2)
// / (B3,nullptr,C3). Batched grid (512): XCD-swizzled (bz, tile).
// TB=false staging optionally applies v*(1/bsc[0]) + bsb[col] (vals spectral-norm).
template<bool TB, bool BATCHED>
__global__ __launch_bounds__(256) void gemm_mfma(
    const float* __restrict__ A, const float* __restrict__ B, float* __restrict__ C,
    long long sA, long long sB, long long sC,
    const float* __restrict__ bias,
    const float* __restrict__ scale_ptr, int sstride, int smode,
    float* __restrict__ norm_out,
    float* __restrict__ att_out,
    const float* __restrict__ B2, const float* __restrict__ bias2, float* __restrict__ C2,
    const float* __restrict__ B3, float* __restrict__ C3,
    const float* __restrict__ bsc, const float* __restrict__ bsb)
{
  __shared__ short sAhi[128 * 32], sAlo[128 * 32];
  __shared__ short sBhi[128 * 40], sBlo[128 * 40];

  int bz, m0, n0;
  if constexpr (BATCHED) {
    int lin = blockIdx.x;
    int xcd = lin & 7;
    int s = lin >> 3;
    bz = xcd * 16 + (s >> 2);
    int tile = s & 3;
    m0 = (tile >> 1) * 128;
    n0 = (tile & 1) * 128;
  } else {
    bz = 0;
    m0 = blockIdx.y * 128;
    n0 = (blockIdx.x & 1) * 128;
    int sel = blockIdx.x >> 1;
    if (sel == 1) { B = B2; bias = bias2; C = C2; }
    else if (sel == 2) { B = B3; bias = nullptr; C = C3; }
  }
  A += (long long)bz * sA;
  B += (long long)bz * sB;
  C += (long long)bz * sC;

  const int t = threadIdx.x;
  const int lane = t & 63;
  const int wave = t >> 6;
  const int wm = wave >> 1, wn = wave & 1;
  const int q = lane >> 4, c16 = lane & 15;

  // ---- alpha (and rho for smode 3) before the k-loop ----
  float alpha = 1.0f;
  if (smode == 1) alpha = 1.0f / scale_ptr[bz * sstride];
  else if (smode == 2) alpha = scale_ptr[bz * sstride];
  else if (smode == 3) {
    float a2 = 0.f, w = 1.0f;
    #pragma unroll
    for (int i2 = 0; i2 <= 12; i2++) {
      const float* p = scale_ptr + i2 * 512 + bz * 4;
      a2 += w * 0.5f * logf(p[0] + p[1] + p[2] + p[3]);
      w *= 0.5f;
    }
    alpha = expf(-a2);
  }

  float rinv_att = alpha;
  const bool do_att = (att_out != nullptr) && (n0 == 0);

  float binv = 1.0f;
  if (bsc) binv = 1.0f / bsc[0];

  floatx4 acc[4][4];
  #pragma unroll
  for (int i = 0; i < 4; i++)
    #pragma unroll
    for (int j = 0; j < 4; j++)
      acc[i][j] = (floatx4){0.f, 0.f, 0.f, 0.f};

  for (int k0 = 0; k0 < 256; k0 += 32) {
    #pragma unroll
    for (int i = 0; i < 4; i++) {
      int f = t + i * 256;
      int row = f >> 3, c4 = f & 7;
      f4v v = *(const f4v*)(A + (long long)(m0 + row) * 256 + k0 + c4 * 4);
      if (do_att)
        *(f4v*)(att_out + (long long)bz * MAT + (long long)(m0 + row) * 256 + k0 + c4 * 4)
            = v * rinv_att;
      short4v h, l;
      #pragma unroll
      for (int e = 0; e < 4; e++) {
        short hh = f2bf(v[e]);
        h[e] = hh;
        l[e] = f2bf(v[e] - bf2f(hh));
      }
      *(short4v*)&sAhi[row * 32 + c4 * 4] = h;
      *(short4v*)&sAlo[row * 32 + c4 * 4] = l;
    }
    if constexpr (TB) {
      #pragma unroll
      for (int i = 0; i < 4; i++) {
        int f = t + i * 256;
        int row = f >> 3, c4 = f & 7;
        f4v v = *(const f4v*)(B + (long long)(n0 + row) * 256 + k0 + c4 * 4);
        short4v h, l;
        #pragma unroll
        for (int e = 0; e < 4; e++) {
          short hh = f2bf(v[e]);
          h[e] = hh;
          l[e] = f2bf(v[e] - bf2f(hh));
        }
        *(short4v*)&sBhi[row * 40 + c4 * 4] = h;
        *(short4v*)&sBlo[row * 40 + c4 * 4] = l;
      }
      __syncthreads();
    } else {
      __shared__ float sT[32 * 132];
      #pragma unroll
      for (int i = 0; i < 4; i++) {
        int f = t + i * 256;
        int kk = f >> 5, n4 = f & 31;
        f4v v = *(const f4v*)(B + (long long)(k0 + kk) * 256 + n0 + n4 * 4);
        if (bsb) {
          #pragma unroll
          for (int e = 0; e < 4; e++) v[e] = v[e] * binv + bsb[n0 + n4 * 4 + e];
        }
        *(f4v*)&sT[kk * 132 + n4 * 4] = v;
      }
      __syncthreads();
      int n = t & 127, kh = t >> 7;
      short8v h0, h1, l0, l1;
      #pragma unroll
      for (int j = 0; j < 8; j++) {
        float x0 = sT[(kh * 16 + j) * 132 + n];
        float x1 = sT[(kh * 16 + 8 + j) * 132 + n];
        short a0 = f2bf(x0), a1 = f2bf(x1);
        h0[j] = a0; l0[j] = f2bf(x0 - bf2f(a0));
        h1[j] = a1; l1[j] = f2bf(x1 - bf2f(a1));
      }
      *(short8v*)&sBhi[n * 40 + kh * 16] = h0;
      *(short8v*)&sBhi[n * 40 + kh * 16 + 8] = h1;
      *(short8v*)&sBlo[n * 40 + kh * 16] = l0;
      *(short8v*)&sBlo[n * 40 + kh * 16 + 8] = l1;
      __syncthreads();
    }

    short8v ah[4], al[4], bh[4], bl[4];
    #pragma unroll
    for (int fi = 0; fi < 4; fi++) {
      int r = wm * 64 + fi * 16 + c16;
      ah[fi] = *(short8v*)&sAhi[r * 32 + q * 8];
      al[fi] = *(short8v*)&sAlo[r * 32 + q * 8];
    }
    #pragma unroll
    for (int fj = 0; fj < 4; fj++) {
      int r = wn * 64 + fj * 16 + c16;
      bh[fj] = *(short8v*)&sBhi[r * 40 + q * 8];
      bl[fj] = *(short8v*)&sBlo[r * 40 + q * 8];
    }
    #pragma unroll
    for (int fi = 0; fi < 4; fi++)
      #pragma unroll
      for (int fj = 0; fj < 4; fj++) {
        acc[fi][fj] = __builtin_amdgcn_mfma_f32_16x16x32_bf16(al[fi], bh[fj], acc[fi][fj], 0, 0, 0);
        acc[fi][fj] = __builtin_amdgcn_mfma_f32_16x16x32_bf16(ah[fi], bl[fj], acc[fi][fj], 0, 0, 0);
        acc[fi][fj] = __builtin_amdgcn_mfma_f32_16x16x32_bf16(ah[fi], bh[fj], acc[fi][fj], 0, 0, 0);
      }
    __syncthreads();
  }

  float ssq = 0.f;
  #pragma unroll
  for (int fi = 0; fi < 4; fi++) {
    #pragma unroll
    for (int fj = 0; fj < 4; fj++) {
      int col = n0 + wn * 64 + fj * 16 + c16;
      float bb = bias ? bias[col] : 0.f;
      #pragma unroll
      for (int r = 0; r < 4; r++) {
        int row = m0 + wm * 64 + fi * 16 + q * 4 + r;
        float v = acc[fi][fj][r] * alpha + bb;
        C[(long long)row * 256 + col] = v;
        ssq += v * v;
      }
    }
  }

  if (norm_out) {
    float* red = (float*)sAhi;
    red[t] = ssq;
    __syncthreads();
    for (int off = 128; off > 0; off >>= 1) {
      if (t < off) red[t] += red[t + off];
      __syncthreads();
    }
    if (t == 0) {
      int tl = ((m0 >> 7) << 1) | (n0 >> 7);
      norm_out[bz * 4 + tl] = red[0];
    }
  }
}

// ---------------- chain epilogue: alpha*acc -> bf16 M (row-major) + per-tile norm ---
__device__ __forceinline__ void chain_epilogue(
    short* LB, float* red, floatx4 (&acc)[4][4], float alpha,
    int m0, int n0, int wm, int wn, int q, int c16, int t,
    short* __restrict__ Mout,
    float* __restrict__ nout, int bz, int tile, bool write_out)
{
  __syncthreads();  // all LDS reads of the k-loop done before LB reuse
  float ssq = 0.f;
  #pragma unroll
  for (int fi = 0; fi < 4; fi++)
    #pragma unroll
    for (int fj = 0; fj < 4; fj++) {
      int lcol = wn * 64 + fj * 16 + c16;
      #pragma unroll
      for (int r = 0; r < 4; r++) {
        int lrow = wm * 64 + fi * 16 + q * 4 + r;
        float v = acc[fi][fj][r] * alpha;
        ssq += v * v;
        if (write_out) LB[lrow * 128 + lcol] = f2bf(v);
      }
    }

  if (write_out) {
    __syncthreads();
    int lr = t >> 1, off = (t & 1) * 64;
    #pragma unroll
    for (int jc = 0; jc < 8; jc++)
      *(short8v*)(Mout + (long long)(m0 + lr) * 256 + n0 + off + jc * 8)
          = *(const short8v*)&LB[lr * 128 + off + jc * 8];
  }

  red[t] = ssq;
  __syncthreads();
  for (int off2 = 128; off2 > 0; off2 >>= 1) {
    if (t < off2) red[t] += red[t + off2];
    __syncthreads();
  }
  if (t == 0) nout[bz * 4 + tile] = red[0];
}

// ---------------- squaring 1: fp32 S (split 3-MFMA) -> bf16 M ----------------------
__global__ __launch_bounds__(256) void sq_f32bf(
    const float* __restrict__ S, short* __restrict__ Mo,
    const float* __restrict__ nprev, float* __restrict__ nout)
{
  __shared__ short SM[18432];      // sAhi|sAlo|sBhi|sBlo ; epilogue LB (16384)
  __shared__ float sT[32 * 132];
  __shared__ float red[256];
  short* sAhi = SM;
  short* sAlo = SM + 4096;
  short* sBhi = SM + 8192;
  short* sBlo = SM + 13312;

  int lin = blockIdx.x;
  int xcd = lin & 7, s = lin >> 3;
  int bz = xcd * 16 + (s >> 2);
  int tile = s & 3;
  int m0 = (tile >> 1) * 128, n0 = (tile & 1) * 128;
  const float* A = S + (long long)bz * MAT;

  const int t = threadIdx.x;
  const int lane = t & 63;
  const int wave = t >> 6;
  const int wm = wave >> 1, wn = wave & 1;
  const int q = lane >> 4, c16 = lane & 15;

  floatx4 acc[4][4];
  #pragma unroll
  for (int i = 0; i < 4; i++)
    #pragma unroll
    for (int j = 0; j < 4; j++)
      acc[i][j] = (floatx4){0.f, 0.f, 0.f, 0.f};

  for (int k0 = 0; k0 < 256; k0 += 32) {
    #pragma unroll
    for (int i = 0; i < 4; i++) {
      int f = t + i * 256;
      int row = f >> 3, c4 = f & 7;
      f4v v = *(const f4v*)(A + (long long)(m0 + row) * 256 + k0 + c4 * 4);
      short4v h, l;
      #pragma unroll
      for (int e = 0; e < 4; e++) {
        short hh = f2bf(v[e]);
        h[e] = hh;
        l[e] = f2bf(v[e] - bf2f(hh));
      }
      *(short4v*)&sAhi[row * 32 + c4 * 4] = h;
      *(short4v*)&sAlo[row * 32 + c4 * 4] = l;
    }
    #pragma unroll
    for (int i = 0; i < 4; i++) {
      int f = t + i * 256;
      int kk = f >> 5, n4 = f & 31;
      f4v v = *(const f4v*)(A + (long long)(k0 + kk) * 256 + n0 + n4 * 4);
      *(f4v*)&sT[kk * 132 + n4 * 4] = v;
    }
    __syncthreads();
    {
      int n = t & 127, kh = t >> 7;
      short8v h0, h1, l0, l1;
      #pragma unroll
      for (int j = 0; j < 8; j++) {
        float x0 = sT[(kh * 16 + j) * 132 + n];
        float x1 = sT[(kh * 16 + 8 + j) * 132 + n];
        short a0 = f2bf(x0), a1 = f2bf(x1);
        h0[j] = a0; l0[j] = f2bf(x0 - bf2f(a0));
        h1[j] = a1; l1[j] = f2bf(x1 - bf2f(a1));
      }
      *(short8v*)&sBhi[n * 40 + kh * 16] = h0;
      *(short8v*)&sBhi[n * 40 + kh * 16 + 8] = h1;
      *(short8v*)&sBlo[n * 40 + kh * 16] = l0;
      *(short8v*)&sBlo[n * 40 + kh * 16 + 8] = l1;
    }
    __syncthreads();

    short8v ah[4], al[4], bh[4], bl[4];
    #pragma unroll
    for (int fi = 0; fi < 4; fi++) {
      int r = wm * 64 + fi * 16 + c16;
      ah[fi] = *(short8v*)&sAhi[r * 32 + q * 8];
      al[fi] = *(short8v*)&sAlo[r * 32 + q * 8];
    }
    #pragma unroll
    for (int fj = 0; fj < 4; fj++) {
      int r = wn * 64 + fj * 16 + c16;
      bh[fj] = *(short8v*)&sBhi[r * 40 + q * 8];
      bl[fj] = *(short8v*)&sBlo[r * 40 + q * 8];
    }
    #pragma unroll
    for (int fi = 0; fi < 4; fi++)
      #pragma unroll
      for (int fj = 0; fj < 4; fj++) {
        acc[fi][fj] = __builtin_amdgcn_mfma_f32_16x16x32_bf16(al[fi], bh[fj], acc[fi][fj], 0, 0, 0);
        acc[fi][fj] = __builtin_amdgcn_mfma_f32_16x16x32_bf16(ah[fi], bl[fj], acc[fi][fj], 0, 0, 0);
        acc[fi][fj] = __builtin_amdgcn_mfma_f32_16x16x32_bf16(ah[fi], bh[fj], acc[fi][fj], 0, 0, 0);
      }
    __syncthreads();
  }

  const float* p = nprev + bz * 4;
  float alpha = 1.0f / (p[0] + p[1] + p[2] + p[3]);
  chain_epilogue(SM, red, acc, alpha, m0, n0, wm, wn, q, c16, t,
                 Mo + (long long)bz * MAT, nout, bz, tile, true);
}

// ---------------- squarings 2..12: pure bf16, M-only, LDS-transposed B -------------
template<bool WRITE_OUT>
__global__ __launch_bounds__(256) void sq_bf(
    const short* __restrict__ Mi, short* __restrict__ Mo,
    const float* __restrict__ nprev, float* __restrict__ nout)
{
  __shared__ short SMEM[16384];   // Bs = [128][36] (4608 shorts) ; epilogue LB
  __shared__ float red[256];
  short* Bs = SMEM;

  int lin = blockIdx.x;
  int xcd = lin & 7, s = lin >> 3;
  int bz = xcd * 16 + (s >> 2);
  int tile = s & 3;
  int m0 = (tile >> 1) * 128, n0 = (tile & 1) * 128;

  const short* A = Mi + (long long)bz * MAT;

  const int t = threadIdx.x;
  const int lane = t & 63;
  const int wave = t >> 6;
  const int wm = wave >> 1, wn = wave & 1;
  const int q = lane >> 4, c16 = lane & 15;
  const int g = t >> 5, cc = t & 31;   // staging: 8 row-groups x 32 col-chunks

  floatx4 acc[4][4];
  #pragma unroll
  for (int i = 0; i < 4; i++)
    #pragma unroll
    for (int j = 0; j < 4; j++)
      acc[i][j] = (floatx4){0.f, 0.f, 0.f, 0.f};

  for (int k0 = 0; k0 < 256; k0 += 32) {
    __syncthreads();   // previous iteration's Bs reads done
    // stage B^T tile: Bs[n][kk] = M[k0+kk][n0+n], kk in [0,32), n in [0,128)
    short4v r0 = *(const short4v*)(A + (long long)(k0 + g * 4 + 0) * 256 + n0 + cc * 4);
    short4v r1 = *(const short4v*)(A + (long long)(k0 + g * 4 + 1) * 256 + n0 + cc * 4);
    short4v r2 = *(const short4v*)(A + (long long)(k0 + g * 4 + 2) * 256 + n0 + cc * 4);
    short4v r3 = *(const short4v*)(A + (long long)(k0 + g * 4 + 3) * 256 + n0 + cc * 4);
    #pragma unroll
    for (int j = 0; j < 4; j++) {
      short4v w4 = (short4v){r0[j], r1[j], r2[j], r3[j]};
      *(short4v*)&Bs[(cc * 4 + j) * 36 + g * 4] = w4;   // b64 write, ~4-way
    }
    __syncthreads();

    short8v a[4], b[4];
    #pragma unroll
    for (int fi = 0; fi < 4; fi++)
      a[fi] = *(const short8v*)(A + (long long)(m0 + wm * 64 + fi * 16 + c16) * 256 + k0 + q * 8);
    #pragma unroll
    for (int fj = 0; fj < 4; fj++) {
      int n = wn * 64 + fj * 16 + c16;
      short4v lo = *(const short4v*)&Bs[n * 36 + q * 8];
      short4v hi = *(const short4v*)&Bs[n * 36 + q * 8 + 4];
      b[fj] = __builtin_shufflevector(lo, hi, 0, 1, 2, 3, 4, 5, 6, 7);
    }
    #pragma unroll
    for (int fi = 0; fi < 4; fi++)
      #pragma unroll
      for (int fj = 0; fj < 4; fj++)
        acc[fi][fj] = __builtin_amdgcn_mfma_f32_16x16x32_bf16(a[fi], b[fj], acc[fi][fj], 0, 0, 0);
  }

  const float* p = nprev + bz * 4;
  float alpha = 1.0f / (p[0] + p[1] + p[2] + p[3]);
  chain_epilogue(SMEM, red, acc, alpha, m0, n0, wm, wn, q, c16, t,
                 WRITE_OUT ? Mo + (long long)bz * MAT : nullptr,
                 nout, bz, tile, WRITE_OUT);
}

// ---------------- sigma: 1024-thread power iteration, LDS-cached bf16 W ------------
__device__ __forceinline__ float bsum1024(float x, float* red, int t)
{
  red[t] = x; __syncthreads();
  for (int off = 512; off > 0; off >>= 1) {
    if (t < off) red[t] += red[t + off];
    __syncthreads();
  }
  float r = red[0];
  __syncthreads();
  return r;
}

__global__ __launch_bounds__(1024) void sigma_kernel(
    const float* __restrict__ W, const float* __restrict__ u0, float* __restrict__ sigma)
{
  __shared__ short Wl[65536];
  __shared__ float u[256], v[256], red[1024];
  int t = threadIdx.x;
  int r = t & 255, seg = t >> 8;
  const float eps = 1e-12f;

  #pragma unroll
  for (int i = 0; i < 16; i++) {
    int idx = (i * 1024 + t) * 4;
    f4v w = *(const f4v*)(W + idx);
    short4v h;
    #pragma unroll
    for (int e = 0; e < 4; e++) h[e] = f2bf(w[e]);
    *(short4v*)&Wl[idx] = h;
  }

  float x = (t < 256) ? u0[t] : 0.f;
  float nrm = sqrtf(bsum1024(x * x, red, t));
  if (t < 256) u[t] = x / (nrm + eps);
  __syncthreads();

  for (int it = 0; it < 5; it++) {
    float sv = 0.f;
    #pragma unroll 8
    for (int j = 0; j < 64; j++) {
      int h = seg * 64 + j;
      sv = fmaf(bf2f(Wl[h * 256 + r]), u[h], sv);
    }
    red[t] = sv; __syncthreads();
    float vr = 0.f;
    if (t < 256) vr = red[t] + red[256 + t] + red[512 + t] + red[768 + t];
    __syncthreads();
    nrm = sqrtf(bsum1024(t < 256 ? vr * vr : 0.f, red, t));
    if (t < 256) v[t] = vr / (nrm + eps);
    __syncthreads();
    if (it < 4) {
      float su = 0.f;
      #pragma unroll
      for (int j = 0; j < 16; j++) {
        short4v w4 = *(const short4v*)&Wl[r * 256 + seg * 64 + j * 4];
        const float* vv = &v[seg * 64 + j * 4];
        su += bf2f(w4[0]) * vv[0] + bf2f(w4[1]) * vv[1]
            + bf2f(w4[2]) * vv[2] + bf2f(w4[3]) * vv[3];
      }
      red[t] = su; __syncthreads();
      float ur = 0.f;
      if (t < 256) ur = red[t] + red[256 + t] + red[512 + t] + red[768 + t];
      __syncthreads();
      nrm = sqrtf(bsum1024(t < 256 ? ur * ur : 0.f, red, t));
      if (t < 256) u[t] = ur / (nrm + eps);
      __syncthreads();
    }
  }

  // sigma = ||W v5|| in fp32 (u5 = Wv5/||Wv5|| => u5.(W v5) = ||W v5||)
  float z = 0.f;
  #pragma unroll
  for (int j = 0; j < 16; j++) {
    f4v w = *(const f4v*)(W + r * 256 + seg * 64 + j * 4);
    const float* vv = &v[seg * 64 + j * 4];
    z += w[0] * vv[0] + w[1] * vv[1] + w[2] * vv[2] + w[3] * vv[3];
  }
  red[t] = z; __syncthreads();
  float zr = 0.f;
  if (t < 256) zr = red[t] + red[256 + t] + red[512 + t] + red[768 + t];
  __syncthreads();
  float zz = bsum1024(t < 256 ? zr * zr : 0.f, red, t);
  if (t == 0) sigma[0] = sqrtf(zz);
}

extern "C" void kernel_launch(void* const* d_in, const int* in_sizes, int n_in,
                              void* d_out, int out_size, void* d_ws, size_t ws_size,
                              hipStream_t stream)
{
  const float* x  = (const float*)d_in[0];
  const float* Wq = (const float*)d_in[1];
  const float* bq = (const float*)d_in[2];
  const float* Wk = (const float*)d_in[3];
  const float* bk = (const float*)d_in[4];
  const float* Wv = (const float*)d_in[5];
  const float* bv = (const float*)d_in[6];
  const float* u0 = (const float*)d_in[7];

  float* out  = (float*)d_out;
  float* out0 = out;             // q -> chain scratch -> weighted
  float* out1 = out + BIG;       // k -> chain scratch -> attention
  short* out0s = (short*)out0;
  short* out1s = (short*)out1;

  float* ws         = (float*)d_ws;
  float* scores_buf = ws;          // [B,N,N] fp32 raw scores
  float* vals_buf   = ws + BIG;    // [B,N,D] RAW x@Wv^T (no sigma, no bias)
  float* partials   = ws + 2 * BIG;   // [13][128][4] per-tile norm^2
  float* sigma      = partials + 13 * 512;

  dim3 blk(256);

  // 1) fused projections: q -> out0, k -> out1, raw vals -> ws
  gemm_mfma<true, false><<<dim3(6, 256, 1), blk, 0, stream>>>(
      x, Wq, out0, 0, 0, 0, bq, nullptr, 0, 0, nullptr, nullptr,
      Wk, bk, out1, Wv, vals_buf, nullptr, nullptr);

  // 2) scores = q @ k^T -> ws (fp32), per-tile norm^2 -> slot 0
  gemm_mfma<true, true><<<dim3(512, 1, 1), blk, 0, stream>>>(
      out0, out1, scores_buf, MAT, MAT, MAT, nullptr, nullptr, 0, 0, partials,
      nullptr, nullptr, nullptr, nullptr, nullptr, nullptr, nullptr, nullptr);

  // 3) sigma power iteration (deliberately NOT dispatch 0 — overhead A/B test)
  sigma_kernel<<<1, dim3(1024), 0, stream>>>(Wv, u0, sigma);

  // 4) squaring 1: S (fp32, split) -> bf16 M1 in out0s, norm slot 1
  sq_f32bf<<<dim3(512, 1, 1), blk, 0, stream>>>(scores_buf, out0s, partials, partials + 512);

  // 5) squarings 2..11: bf16 M-only chain (L2-resident per XCD)
  const short* cin = out0s;
  for (int i = 0; i < 10; i++) {
    short* cout = (i & 1) ? out0s : out1s;
    sq_bf<true><<<dim3(512, 1, 1), blk, 0, stream>>>(cin, cout,
        partials + (1 + i) * 512, partials + (2 + i) * 512);
    cin = cout;
  }
  // 6) squaring 12: norm only (slot 12); input is out0s after 10 steps
  sq_bf<false><<<dim3(512, 1, 1), blk, 0, stream>>>(cin, nullptr,
      partials + 11 * 512, partials + 12 * 512);

  // 7) final: weighted = (S @ (vals/sigma + bv)) * rho_inv -> out0,
  //    attention = S * rho_inv -> out1 (A-staging), rho_inv computed inline.
  gemm_mfma<false, true><<<dim3(512, 1, 1), blk, 0, stream>>>(
      scores_buf, vals_buf, out0, MAT, MAT, MAT, nullptr, partials, 0, 3, nullptr,
      out1, nullptr, nullptr, nullptr, nullptr, nullptr, sigma, bv);
}